// Round 6
// baseline (460.555 us; speedup 1.0000x reference)
//
#include <hip/hip_runtime.h>

// Stride-2 valid conv as implicit GEMM on MFMA (bf16 in, fp32 acc).
// GEMM: M=cout=256, N=b*oh*ow=96800, K=tap*cin=1152.
// R9: R8 (AITER-flatmm structure: B global->VGPR direct from parity-split
//     layout, reg-dbuf, counted vmcnt(16); A-only LDS dbuf 2x16KB) with the
//     relayout stride bug fixed: per-(b,h) row is 112 16B-units (2 parity x
//     56 w2), phase-2 store stride was 224 (overflowed xs into wt; conv read
//     garbage). Exact bijection verified: max idx = 16*CPLANE - 1.

#define BATCH 32
#define CIN   128
#define H     112
#define W     112
#define COUT  256
#define OH    55
#define OW    55
#define NPIX  (OH*OW)          // 3025
#define NTOT  (BATCH*NPIX)     // 96800

#define BM    128
#define BN    192
#define NB_N  ((NTOT + BN - 1) / BN)   // 505
#define NBLK  (2 * NB_N)               // 1010

#define CPLANE (BATCH*H*112)           // 16B-units per c8 plane = 401408
#define BSTRIDE (H*112)                // 12544 16B-units per b within a plane

typedef __bf16 bf16x8 __attribute__((ext_vector_type(8)));
typedef float  f32x4  __attribute__((ext_vector_type(4)));

__device__ __forceinline__ unsigned short f2bf(float f) {
    unsigned u = __float_as_uint(f);
    u += 0x7FFFu + ((u >> 16) & 1u);   // RNE
    return (unsigned short)(u >> 16);
}

__device__ __forceinline__ void gld_lds16(const void* g, void* l) {
    __builtin_amdgcn_global_load_lds((__attribute__((address_space(1))) void*)g,
                                     (__attribute__((address_space(3))) void*)l,
                                     16, 0, 0);
}

// ---------- fused prepass ----------
// blocks [0, BATCH*H): x NCHW fp32 -> xs16[c8][b][h][w&1][w>>1] (8 cin each)
// blocks [BATCH*H, +1152): w (COUT,CIN,3,3) fp32 -> wt[tap][cout][cin] bf16
#define XP 136   // LDS pitch in shorts (272 B, 16-B aligned)
#define WBLK ((9*COUT*CIN + 255)/256)  // 1152
__global__ __launch_bounds__(256) void relayout_k(const float* __restrict__ x,
                                                  const float* __restrict__ w,
                                                  unsigned short* __restrict__ xs,
                                                  unsigned short* __restrict__ wt) {
    if (blockIdx.x >= BATCH * H) {
        int o = (blockIdx.x - BATCH * H) * 256 + threadIdx.x;
        if (o < 9 * COUT * CIN) {
            int cin  = o & (CIN - 1);
            int r    = o >> 7;
            int cout = r & (COUT - 1);
            int tap  = r >> 8;
            wt[o] = f2bf(w[((size_t)cout * CIN + cin) * 9 + tap]);
        }
        return;
    }
    __shared__ __align__(16) unsigned short tile[W * XP];
    const int bh = blockIdx.x;
    const int b  = bh / H;
    const int h  = bh - b * H;
    const float* xr = x + (size_t)b * CIN * (H * W) + (size_t)h * W;
    const int t = threadIdx.x;
    // phase 1: per unit, two float4 loads (c, c+1), pair-writes (ushort2) with
    // per-row 16B-slot rotation (c8+2w)&15 -> writes spread over 8 banks.
#pragma unroll
    for (int i = 0; i < 7; ++i) {
        int e  = t + i * 256;            // < 1792 = 64 cpairs * 28 w4
        int cp = e / 28;
        int w4 = e - cp * 28;
        int c  = cp * 2;
        float4 v0 = *(const float4*)(xr + (size_t)c * (H * W) + w4 * 4);
        float4 v1 = *(const float4*)(xr + (size_t)(c + 1) * (H * W) + w4 * 4);
        int c8 = c >> 3;
        int cl = c & 7;                  // even
        float a0[4] = {v0.x, v0.y, v0.z, v0.w};
        float a1[4] = {v1.x, v1.y, v1.z, v1.w};
#pragma unroll
        for (int j = 0; j < 4; ++j) {
            int ww  = w4 * 4 + j;
            int idx = ww * XP + ((c8 + 2 * ww) & 15) * 8 + cl;
            *(ushort2*)(tile + idx) = (ushort2){f2bf(a0[j]), f2bf(a1[j])};
        }
    }
    __syncthreads();
    // phase 2: b128 LDS reads (rotation-aware), parity-split global stores.
    // idx16(c8,b,h,p,w2) = c8*CPLANE + (b*H+h)*112 + p*56 + w2.
    uint4* xsq = (uint4*)xs;
#pragma unroll
    for (int i = 0; i < 7; ++i) {
        int e  = t + i * 256;            // < 1792 = 16*112
        int c8 = e / 112;
        int ww = e - c8 * 112;
        int idx = c8 * CPLANE + (b * H + h) * 112 + (ww & 1) * 56 + (ww >> 1);
        xsq[idx] = *(const uint4*)(tile + ww * XP + ((c8 + 2 * ww) & 15) * 8);
    }
}

// ---------- main: BM=128 x BN=192, 4 waves (2Mx2N, wave 64x96) ----------
// A: LDS dbuf 2x16KB (XOR-swizzled, gld_lds). B: global->VGPR direct, register
// double-buffered (12 bf16x8 per set). Counted vmcnt(16) = A(kt+1)4 + B(kt+1)12.
__global__ __launch_bounds__(256, 2) void conv_mfma_k(const unsigned short* __restrict__ xs,
                                                      const unsigned short* __restrict__ wt,
                                                      float* __restrict__ out) {
    __shared__ __align__(16) unsigned short L[2][BM * 64];   // 2 x 16 KB

    const int tid  = threadIdx.x;
    const int wave = tid >> 6;
    const int lane = tid & 63;
    const int wm   = wave >> 1;            // 0..1 -> M offset wm*64
    const int wn   = wave & 1;             // 0..1 -> N offset wn*96
    const int lrow = lane & 15;
    const int kg   = lane >> 4;            // k-chunk group 0..3

    // bijective XCD swizzle (m204), NBLK = 1010 = 8*126 + 2
    const int xcd = blockIdx.x & 7;
    const int lin = blockIdx.x >> 3;
    const int q = NBLK >> 3, r = NBLK & 7;
    const int bswz = (xcd < r ? xcd * (q + 1) : r * (q + 1) + (xcd - r) * q) + lin;
    const int m0 = (bswz & 1) * BM;        // M-half; pair shares B reads in L2
    const int n0 = (bswz >> 1) * BN;

    // ---- A staging constants (R6 pattern, A-only) ----
    const int rA  = tid >> 3;                          // 0..31
    const int sx8 = ((tid & 7) ^ (rA & 7)) * 8;        // pre-swizzled source chunk
    auto stageA = [&](int kt, int buf) {
        const int tap  = kt >> 1;
        const int cin0 = (kt & 1) * 64;
        const unsigned short* wsrc = wt + tap * (COUT * CIN) + (m0 + rA) * CIN + cin0 + sx8;
        unsigned short* lb = &L[buf][0];
#pragma unroll
        for (int c = 0; c < 4; ++c)        // 4 calls x 4 KB (32 rows each)
            gld_lds16(wsrc + c * 32 * CIN, lb + c * 2048 + wave * 512);
    };

    // ---- B per-lane base offsets (16-B units into xs) ----
    // pixel nn=(b,oh,ow), tap (r2,s), chunk c8 = (kt&1)*8 + kh*4 + kg:
    // idx16 = c8*CPLANE + b*BSTRIDE + (2*oh + r2)*112 + (s&1)*56 + ow + (s>>1)
    int C0[6];
#pragma unroll
    for (int ni = 0; ni < 6; ++ni) {
        int nn = n0 + wn * 96 + ni * 16 + lrow;
        if (nn >= NTOT) nn = NTOT - 1;
        int b  = nn / NPIX;
        int rp = nn - b * NPIX;
        int oh = rp / OW;
        int ow = rp - oh * OW;
        C0[ni] = b * BSTRIDE + oh * 224 + ow + kg * CPLANE;
    }

    auto issueB = [&](int kt, bf16x8* Br) {
        const int tap = kt >> 1;
        const int r2  = (tap >= 6) ? 2 : (tap >= 3) ? 1 : 0;
        const int s   = tap - 3 * r2;
        const int sc  = r2 * 112 + (s & 1) * 56 + (s >> 1) + (kt & 1) * (8 * CPLANE);
#pragma unroll
        for (int kh = 0; kh < 2; ++kh)
#pragma unroll
            for (int ni = 0; ni < 6; ++ni)
                Br[kh * 6 + ni] = *(const bf16x8*)(xs + (size_t)(C0[ni] + sc + kh * (4 * CPLANE)) * 8);
    };

    // A read offsets (swizzled): row = wm*64 + mi*16 + lrow, slot = (kh*4+kg)^(lrow&7)
    const int aoff = (wm * 64 + lrow) * 64;
    const int sxk0 = ((0 + kg) ^ (lrow & 7)) * 8;
    const int sxk1 = ((4 + kg) ^ (lrow & 7)) * 8;

    f32x4 acc[4][6];
#pragma unroll
    for (int mi = 0; mi < 4; ++mi)
#pragma unroll
        for (int ni = 0; ni < 6; ++ni)
            acc[mi][ni] = (f32x4){0.f, 0.f, 0.f, 0.f};

    bf16x8 Bc[12], Bn[12];
    stageA(0, 0);
    issueB(0, Bc);
    stageA(1, 1);

    for (int kt2 = 0; kt2 < 18; kt2 += 2) {
        // ================= even tile kt2, buf 0 =================
        issueB(kt2 + 1, Bn);                               // always valid (<=17)
        asm volatile("s_waitcnt vmcnt(16)" ::: "memory");  // A(kt2)+B(kt2) done
        asm volatile("s_barrier" ::: "memory");
        {
            const unsigned short* Lb = &L[0][0];
            bf16x8 a0[4], a1[4];
#pragma unroll
            for (int mi = 0; mi < 4; ++mi) {
                a0[mi] = *(const bf16x8*)(Lb + aoff + mi * 1024 + sxk0);
                a1[mi] = *(const bf16x8*)(Lb + aoff + mi * 1024 + sxk1);
            }
            asm volatile("s_barrier" ::: "memory");        // all waves read buf0
            if (kt2 + 2 < 18) stageA(kt2 + 2, 0);          // overwrite under MFMAs
            __builtin_amdgcn_s_setprio(1);
#pragma unroll
            for (int mi = 0; mi < 4; ++mi)
#pragma unroll
                for (int ni = 0; ni < 6; ++ni)
                    acc[mi][ni] = __builtin_amdgcn_mfma_f32_16x16x32_bf16(a0[mi], Bc[ni], acc[mi][ni], 0, 0, 0);
#pragma unroll
            for (int mi = 0; mi < 4; ++mi)
#pragma unroll
                for (int ni = 0; ni < 6; ++ni)
                    acc[mi][ni] = __builtin_amdgcn_mfma_f32_16x16x32_bf16(a1[mi], Bc[6 + ni], acc[mi][ni], 0, 0, 0);
            __builtin_amdgcn_s_setprio(0);
        }
        // ================= odd tile kt2+1, buf 1 =================
        if (kt2 + 2 < 18) {
            issueB(kt2 + 2, Bc);
            asm volatile("s_waitcnt vmcnt(16)" ::: "memory");  // A(kt2+1)+B(kt2+1) done
        } else {
            asm volatile("s_waitcnt vmcnt(0)" ::: "memory");
        }
        asm volatile("s_barrier" ::: "memory");
        {
            const unsigned short* Lb = &L[1][0];
            bf16x8 a0[4], a1[4];
#pragma unroll
            for (int mi = 0; mi < 4; ++mi) {
                a0[mi] = *(const bf16x8*)(Lb + aoff + mi * 1024 + sxk0);
                a1[mi] = *(const bf16x8*)(Lb + aoff + mi * 1024 + sxk1);
            }
            asm volatile("s_barrier" ::: "memory");        // all waves read buf1
            if (kt2 + 3 < 18) stageA(kt2 + 3, 1);
            __builtin_amdgcn_s_setprio(1);
#pragma unroll
            for (int mi = 0; mi < 4; ++mi)
#pragma unroll
                for (int ni = 0; ni < 6; ++ni)
                    acc[mi][ni] = __builtin_amdgcn_mfma_f32_16x16x32_bf16(a0[mi], Bn[ni], acc[mi][ni], 0, 0, 0);
#pragma unroll
            for (int mi = 0; mi < 4; ++mi)
#pragma unroll
                for (int ni = 0; ni < 6; ++ni)
                    acc[mi][ni] = __builtin_amdgcn_mfma_f32_16x16x32_bf16(a1[mi], Bn[6 + ni], acc[mi][ni], 0, 0, 0);
            __builtin_amdgcn_s_setprio(0);
        }
    }

    // epilogue: D col n = lane&15, row m = (lane>>4)*4 + reg
    long obase[6];
    int  okn[6];
#pragma unroll
    for (int ni = 0; ni < 6; ++ni) {
        int nn = n0 + wn * 96 + ni * 16 + lrow;
        okn[ni] = (nn < NTOT);
        if (!okn[ni]) nn = 0;
        int b   = nn / NPIX;
        int pix = nn - b * NPIX;
        obase[ni] = (long)b * (COUT * NPIX) + pix;
    }
    const int mrow = kg * 4;
#pragma unroll
    for (int mi = 0; mi < 4; ++mi) {
#pragma unroll
        for (int rr = 0; rr < 4; ++rr) {
            int  m  = m0 + wm * 64 + mi * 16 + mrow + rr;
            long mo = (long)m * NPIX;
#pragma unroll
            for (int ni = 0; ni < 6; ++ni)
                if (okn[ni]) out[obase[ni] + mo] = acc[mi][ni][rr];
        }
    }
}

// ---------- fallback (ws too small): direct fp32 kernel ----------
__global__ __launch_bounds__(256) void direct_k(const float* __restrict__ x,
                                                const float* __restrict__ w,
                                                float* __restrict__ out) {
    const int pix = blockIdx.x * 256 + threadIdx.x;
    if (pix >= NPIX) return;
    const int b = blockIdx.z, cout0 = blockIdx.y * 8;
    const int oh = pix / OW, ow = pix - oh * OW;
    float acc[8];
#pragma unroll
    for (int i = 0; i < 8; ++i) acc[i] = 0.f;
    const float* xbp = x + ((size_t)b * CIN) * (H * W) + (size_t)(oh * 2) * W + ow * 2;
    const float* wb  = w + (size_t)cout0 * (CIN * 9);
    for (int cin = 0; cin < CIN; ++cin) {
        const float* xp = xbp + (size_t)cin * (H * W);
        float xv[9];
#pragma unroll
        for (int r = 0; r < 3; ++r) {
            xv[r * 3 + 0] = xp[r * W + 0];
            xv[r * 3 + 1] = xp[r * W + 1];
            xv[r * 3 + 2] = xp[r * W + 2];
        }
#pragma unroll
        for (int c = 0; c < 8; ++c) {
            const float* wp = wb + (size_t)c * (CIN * 9) + cin * 9;
#pragma unroll
            for (int k = 0; k < 9; ++k) acc[c] = fmaf(wp[k], xv[k], acc[c]);
        }
    }
    const size_t ob = ((size_t)b * COUT + cout0) * NPIX + pix;
#pragma unroll
    for (int c = 0; c < 8; ++c) out[ob + (size_t)c * NPIX] = acc[c];
}

extern "C" void kernel_launch(void* const* d_in, const int* in_sizes, int n_in,
                              void* d_out, int out_size, void* d_ws, size_t ws_size,
                              hipStream_t stream) {
    const float* x = (const float*)d_in[0];
    const float* w = (const float*)d_in[1];
    float* out = (float*)d_out;

    const size_t xs_elems = (size_t)BATCH * H * W * CIN;
    const size_t wt_elems = (size_t)9 * COUT * CIN;
    const size_t need = (xs_elems + wt_elems) * 2;

    if (ws_size >= need) {
        unsigned short* xs = (unsigned short*)d_ws;
        unsigned short* wt = xs + xs_elems;
        relayout_k<<<dim3(BATCH * H + WBLK), dim3(256), 0, stream>>>(x, w, xs, wt);
        conv_mfma_k<<<dim3(NBLK), dim3(256), 0, stream>>>(xs, wt, out);
    } else {
        dim3 grid((NPIX + 255) / 256, COUT / 8, BATCH);
        direct_k<<<grid, dim3(256), 0, stream>>>(x, w, out);
    }
}